// Round 7
// baseline (256.632 us; speedup 1.0000x reference)
//
#include <hip/hip_runtime.h>
#include <hip/hip_cooperative_groups.h>
#include <cmath>

namespace cg = cooperative_groups;

// SemanticDepthRasterizer — cooperative fused kernel with a non-cooperative
// 3-kernel fallback (same device code paths).
// Phase A: per-gaussian projection/conic (per-block inv(cam2ego) in double).
// Phase B: O(N^2) rank-by-counting == stable argsort-by-z + visible pack,
//          one wave per 64-i chunk, readlane broadcast, global-key prefetch.
// Phase C: depth-segmented tiled compositing (8 waves/block, 8x8 tiles,
//          readlane broadcast, tile-rect cull, deferred semantic loads,
//          TWO-PASS prefix-transmittance combine so LDS stays ~21 KB/block
//          -> >=2 blocks/CU co-resident even under a 64KB/CU occupancy calc).

#define MAXC   16     // semantic channels in this problem instance (C==16)
#define MAXBM  8      // max views supported by per-block E cache
#define NSEG   8      // depth segments == waves per raster block
#define RTPB   (NSEG * 64)
#define ROWS1  9      // combine pass 1 rows: T,D,A,S0..S5
#define ROWS2  10     // combine pass 2 rows: S6..S15
#define INVIS_KEY 0x7FFFFFFF

__device__ __forceinline__ float rlf(float x, int l) {
    return __int_as_float(__builtin_amdgcn_readlane(__float_as_int(x), l));
}

// ---- 4x4 inverse (double, adjugate), top-3-rows result ----
__device__ void inv4x4_rows3(const float* __restrict__ src, float* __restrict__ Eout) {
    double m[16];
#pragma unroll
    for (int j = 0; j < 16; ++j) m[j] = (double)src[j];
    double inv[16];
    inv[0]  =  m[5]*m[10]*m[15] - m[5]*m[11]*m[14] - m[9]*m[6]*m[15] + m[9]*m[7]*m[14] + m[13]*m[6]*m[11] - m[13]*m[7]*m[10];
    inv[4]  = -m[4]*m[10]*m[15] + m[4]*m[11]*m[14] + m[8]*m[6]*m[15] - m[8]*m[7]*m[14] - m[12]*m[6]*m[11] + m[12]*m[7]*m[10];
    inv[8]  =  m[4]*m[9]*m[15]  - m[4]*m[11]*m[13] - m[8]*m[5]*m[15] + m[8]*m[7]*m[13] + m[12]*m[5]*m[11] - m[12]*m[7]*m[9];
    inv[12] = -m[4]*m[9]*m[14]  + m[4]*m[10]*m[13] + m[8]*m[5]*m[14] - m[8]*m[6]*m[13] - m[12]*m[5]*m[10] + m[12]*m[6]*m[9];
    inv[1]  = -m[1]*m[10]*m[15] + m[1]*m[11]*m[14] + m[9]*m[2]*m[15] - m[9]*m[3]*m[14] - m[13]*m[2]*m[11] + m[13]*m[3]*m[10];
    inv[5]  =  m[0]*m[10]*m[15] - m[0]*m[11]*m[14] - m[8]*m[2]*m[15] + m[8]*m[3]*m[14] + m[12]*m[2]*m[11] - m[12]*m[3]*m[10];
    inv[9]  = -m[0]*m[9]*m[15]  + m[0]*m[11]*m[13] + m[8]*m[1]*m[15] - m[8]*m[3]*m[13] - m[12]*m[1]*m[11] + m[12]*m[3]*m[9];
    inv[13] =  m[0]*m[9]*m[14]  - m[0]*m[10]*m[13] - m[8]*m[1]*m[14] + m[8]*m[2]*m[13] + m[12]*m[1]*m[10] - m[12]*m[2]*m[9];
    inv[2]  =  m[1]*m[6]*m[15]  - m[1]*m[7]*m[14]  - m[5]*m[2]*m[15] + m[5]*m[3]*m[14] + m[13]*m[2]*m[7]  - m[13]*m[3]*m[6];
    inv[6]  = -m[0]*m[6]*m[15]  + m[0]*m[7]*m[14]  + m[4]*m[2]*m[15] - m[4]*m[3]*m[14] - m[12]*m[2]*m[7]  + m[12]*m[3]*m[6];
    inv[10] =  m[0]*m[5]*m[15]  - m[0]*m[7]*m[13]  - m[4]*m[1]*m[15] + m[4]*m[3]*m[13] + m[12]*m[1]*m[7]  - m[12]*m[3]*m[5];
    inv[14] = -m[0]*m[5]*m[14]  + m[0]*m[6]*m[13]  + m[4]*m[1]*m[14] - m[4]*m[2]*m[13] - m[12]*m[1]*m[6]  + m[12]*m[2]*m[5];
    inv[3]  = -m[1]*m[6]*m[11]  + m[1]*m[7]*m[10]  + m[5]*m[2]*m[11] - m[5]*m[3]*m[10] - m[9]*m[2]*m[7]   + m[9]*m[3]*m[6];
    inv[7]  =  m[0]*m[6]*m[11]  - m[0]*m[7]*m[10]  - m[4]*m[2]*m[11] + m[4]*m[3]*m[10] + m[8]*m[2]*m[7]   - m[8]*m[3]*m[6];
    inv[11] = -m[0]*m[5]*m[11]  + m[0]*m[7]*m[9]   + m[4]*m[1]*m[11] - m[4]*m[3]*m[9]  - m[8]*m[1]*m[7]   + m[8]*m[3]*m[5];
    inv[15] =  m[0]*m[5]*m[10]  - m[0]*m[6]*m[9]   - m[4]*m[1]*m[10] + m[4]*m[2]*m[9]  + m[8]*m[1]*m[6]   - m[8]*m[2]*m[5];
    double det = m[0]*inv[0] + m[1]*inv[4] + m[2]*inv[8] + m[3]*inv[12];
    double rdet = 1.0 / det;
#pragma unroll
    for (int r = 0; r < 3; ++r)
#pragma unroll
        for (int c = 0; c < 4; ++c)
            Eout[r * 4 + c] = (float)(inv[r * 4 + c] * rdet);
}

// ---------------- phase A: one gaussian projection + conic ----------------
__device__ __forceinline__ void proj_one(
    int gid, int M, int N, int W, int H, const float* __restrict__ Esh,
    const float* __restrict__ means, const float* __restrict__ scales,
    const float* __restrict__ rots,  const float* __restrict__ intr,
    int* __restrict__ ikey, float* __restrict__ uu, float* __restrict__ vv,
    float* __restrict__ cia, float* __restrict__ cib, float* __restrict__ cic,
    float* __restrict__ pr2)
{
    int bm = gid / N;
    int n  = gid - bm * N;
    int b  = bm / M;
    const float* Ep = Esh + bm * 12;
    const float* mp = means + ((size_t)b * N + n) * 3;
    float mx = mp[0], my = mp[1], mz = mp[2];
    float x_c = Ep[0]*mx + Ep[1]*my + Ep[2]*mz  + Ep[3];
    float y_c = Ep[4]*mx + Ep[5]*my + Ep[6]*mz  + Ep[7];
    float z   = Ep[8]*mx + Ep[9]*my + Ep[10]*mz + Ep[11];
    const float* K = intr + (size_t)bm * 16;
    float fx = K[0], fy = K[5], cx = K[2], cy = K[6];
    float zs = fmaxf(z, 1e-4f);
    float u = x_c / zs * fx + cx;
    float v = y_c / zs * fy + cy;
    const float* qp = rots + ((size_t)b * N + n) * 4;
    float qw = qp[0], qx = qp[1], qy = qp[2], qz = qp[3];
    float qn = sqrtf(qw*qw + qx*qx + qy*qy + qz*qz);
    qw /= qn; qx /= qn; qy /= qn; qz /= qn;
    float R00 = 1.f - 2.f*(qy*qy + qz*qz), R01 = 2.f*(qx*qy - qz*qw), R02 = 2.f*(qx*qz + qy*qw);
    float R10 = 2.f*(qx*qy + qz*qw), R11 = 1.f - 2.f*(qx*qx + qz*qz), R12 = 2.f*(qy*qz - qx*qw);
    float R20 = 2.f*(qx*qz - qy*qw), R21 = 2.f*(qy*qz + qx*qw), R22 = 1.f - 2.f*(qx*qx + qy*qy);
    const float* sp = scales + ((size_t)b * N + n) * 3;
    float s0 = sp[0]*sp[0], s1 = sp[1]*sp[1], s2 = sp[2]*sp[2];
    float S00 = R00*R00*s0 + R01*R01*s1 + R02*R02*s2;
    float S01 = R00*R10*s0 + R01*R11*s1 + R02*R12*s2;
    float S02 = R00*R20*s0 + R01*R21*s1 + R02*R22*s2;
    float S11 = R10*R10*s0 + R11*R11*s1 + R12*R12*s2;
    float S12 = R10*R20*s0 + R11*R21*s1 + R12*R22*s2;
    float S22 = R20*R20*s0 + R21*R21*s1 + R22*R22*s2;
    float W00 = Ep[0], W01 = Ep[1], W02 = Ep[2];
    float W10 = Ep[4], W11 = Ep[5], W12 = Ep[6];
    float W20 = Ep[8], W21 = Ep[9], W22 = Ep[10];
    float A00 = W00*S00 + W01*S01 + W02*S02;
    float A01 = W00*S01 + W01*S11 + W02*S12;
    float A02 = W00*S02 + W01*S12 + W02*S22;
    float A10 = W10*S00 + W11*S01 + W12*S02;
    float A11 = W10*S01 + W11*S11 + W12*S12;
    float A12 = W10*S02 + W11*S12 + W12*S22;
    float A20 = W20*S00 + W21*S01 + W22*S02;
    float A21 = W20*S01 + W21*S11 + W22*S12;
    float A22 = W20*S02 + W21*S12 + W22*S22;
    float Sc00 = A00*W00 + A01*W01 + A02*W02;
    float Sc01 = A00*W10 + A01*W11 + A02*W12;
    float Sc02 = A00*W20 + A01*W21 + A02*W22;
    float Sc11 = A10*W10 + A11*W11 + A12*W12;
    float Sc12 = A10*W20 + A11*W21 + A12*W22;
    float Sc22 = A20*W20 + A21*W21 + A22*W22;
    float j00 = fx / zs,  j02 = -fx * x_c / (zs * zs);
    float j11 = fy / zs,  j12 = -fy * y_c / (zs * zs);
    float c00 = j00*j00*Sc00 + 2.f*j00*j02*Sc02 + j02*j02*Sc22;
    float c01 = j00*(Sc01*j11 + Sc02*j12) + j02*(Sc12*j11 + Sc22*j12);
    float c11 = j11*j11*Sc11 + 2.f*j11*j12*Sc12 + j12*j12*Sc22;
    float a  = fmaxf(c00, 0.3f);
    float cc = fmaxf(c11, 0.3f);
    float bb = c01;
    float det = a * cc - bb * bb;
    bool valid = (z > 0.01f) && (det > 1e-8f);
    float det_s = (det > 1e-8f) ? det : 1.0f;
    float ia = cc / det_s, ib = -bb / det_s, ic = a / det_s;
    uu[gid] = u;  vv[gid] = v;
    cia[gid] = ia;  cib[gid] = ib;  cic[gid] = ic;
    // conservative cull radius: lambda_min * dist^2 > 34 -> alpha < ~4e-8
    float dmean = 0.5f * (ia + ic);
    float rad   = sqrtf(fmaxf(0.25f*(ia - ic)*(ia - ic) + ib*ib, 0.f));
    float lmin  = fmaxf(dmean - rad, 1e-12f);
    pr2[gid] = 34.0f / lmin;
    bool visible = valid && (z > 0.1f) &&
                   (u >= 0.f) && (u < (float)W) && (v >= 0.f) && (v < (float)H);
    ikey[gid] = visible ? __float_as_int(z) : INVIS_KEY;
}

// -- phase B: rank one 64-i chunk (stable argsort by z) + pack survivors --
__device__ __forceinline__ void rank_chunk(
    int chunk, int lane, int M, int N, int C,
    const int* __restrict__ ikey,
    const float* __restrict__ uu, const float* __restrict__ vv,
    const float* __restrict__ cia, const float* __restrict__ cib,
    const float* __restrict__ cic, const float* __restrict__ pr2,
    const float* __restrict__ opac, const float* __restrict__ sem,
    float* __restrict__ pu, float* __restrict__ pv,
    float* __restrict__ pia, float* __restrict__ pib, float* __restrict__ pic,
    float* __restrict__ pop, float* __restrict__ pdz, float* __restrict__ prr,
    float* __restrict__ psem, int* __restrict__ pcount)
{
    int nch64 = (N + 63) >> 6;
    int bm = chunk / nch64;
    int cl = chunk - bm * nch64;          // i-chunk index within view
    int i  = (cl << 6) + lane;
    const int* kb = ikey + (size_t)bm * N;
    int ki  = (i < N) ? kb[i] : INVIS_KEY;
    int kip = ki + 1;                     // tie-break: j<i counts kj<=ki
    int rank = 0, tot = 0;
    int kj = (lane < N) ? kb[lane] : INVIS_KEY;   // prefetched chunk 0
    for (int jc = 0; jc < nch64; ++jc) {
        int kcur = kj;
        if (jc + 1 < nch64) {
            int jn = ((jc + 1) << 6) + lane;
            kj = (jn < N) ? kb[jn] : INVIS_KEY;
        }
        tot += (int)__popcll(__ballot(kcur != INVIS_KEY));
        if (jc < cl) {
#pragma unroll
            for (int gg = 0; gg < 64; ++gg)
                rank += (__builtin_amdgcn_readlane(kcur, gg) < kip);
        } else if (jc > cl) {
#pragma unroll
            for (int gg = 0; gg < 64; ++gg)
                rank += (__builtin_amdgcn_readlane(kcur, gg) < ki);
        } else {            // straddle chunk: j < i  <=>  gg < lane
#pragma unroll
            for (int gg = 0; gg < 64; ++gg) {
                int kk = (gg < lane) ? kip : ki;
                rank += (__builtin_amdgcn_readlane(kcur, gg) < kk);
            }
        }
    }
    if (cl == 0 && lane == 0) pcount[bm] = tot;
    if (i < N && ki != INVIS_KEY) {
        int b = bm / M;
        size_t src = (size_t)bm * N + i;
        size_t dst = (size_t)bm * N + rank;
        pu[dst]  = uu[src];   pv[dst]  = vv[src];
        pia[dst] = cia[src];  pib[dst] = cib[src];  pic[dst] = cic[src];
        pop[dst] = opac[(size_t)b * N + i];
        float z  = __int_as_float(ki);
        pdz[dst] = fminf(fmaxf(z, 0.1f), 100.0f);
        prr[dst] = pr2[src];
        const float* spc = sem + ((size_t)b * N + i) * C;
        float* dpc = psem + dst * C;
        int c4 = C & ~3;
        for (int q = 0; q < c4; q += 4)
            *(float4*)(dpc + q) = *(const float4*)(spc + q);
        for (int q = c4; q < C; ++q) dpc[q] = spc[q];
    }
}

// ------- phase C: one 8x8 tile, depth-segmented compositing (8 waves) -------
__device__ __forceinline__ void raster_tile(
    int tile, int wave, int lane, float* comb,
    int BM, int N, int C, int H, int W, int ntx, int nty,
    const float* __restrict__ pu, const float* __restrict__ pv,
    const float* __restrict__ pia, const float* __restrict__ pib,
    const float* __restrict__ pic, const float* __restrict__ pop,
    const float* __restrict__ pdz, const float* __restrict__ prr,
    const float* __restrict__ psem, const int* __restrict__ pcount,
    float* __restrict__ out)
{
    int tpv = ntx * nty;
    int bm  = tile / tpv;
    int rem = tile - bm * tpv;
    int tyi = rem / ntx;
    int txi = rem - tyi * ntx;
    int lx = lane & 7, ly = lane >> 3;
    float fxp = (float)(txi * 8 + lx), fyp = (float)(tyi * 8 + ly);
    float x0 = (float)(txi * 8),     y0 = (float)(tyi * 8);
    float x1 = (float)(txi * 8 + 7), y1 = (float)(tyi * 8 + 7);

    int cnt = pcount[bm];
    int seg = (cnt + NSEG - 1) / NSEG;
    int gs = wave * seg;
    int ge = min(gs + seg, cnt);

    float T = 1.0f, accA = 0.f, accD = 0.f;
    float accS[MAXC];
#pragma unroll
    for (int q = 0; q < MAXC; ++q) accS[q] = 0.f;

    for (int base = gs; base < ge; base += 64) {
        if (!__any(T >= 1e-6f)) break;
        int g = base + lane;
        bool inr = g < ge;
        size_t src = (size_t)bm * N + g;
        float gu = 1e30f, gv = 1e30f, gia = 0.f, gib = 0.f, gic = 0.f,
              gop = 0.f, gdz = 0.f, gr2 = -1.f;
        if (inr) {
            gu  = pu[src];  gv  = pv[src];
            gia = pia[src]; gib = pib[src]; gic = pic[src];
            gop = pop[src]; gdz = pdz[src]; gr2 = prr[src];
        }
        // tile cull: dist^2 from tile rect to center vs r2
        float cxm = fminf(fmaxf(gu, x0), x1);
        float cym = fminf(fmaxf(gv, y0), y1);
        float ddx = gu - cxm, ddy = gv - cym;
        float dist2 = ddx*ddx + ddy*ddy;
        unsigned long long mask = __ballot(inr && (dist2 <= gr2));
        // deferred semantic load: only survivors fetch their channels
        float sf[MAXC];
        if ((mask >> lane) & 1ull) {
            const float4* spc = (const float4*)(psem + src * MAXC);
#pragma unroll
            for (int q = 0; q < MAXC / 4; ++q) {
                float4 f = spc[q];
                sf[q*4+0] = f.x; sf[q*4+1] = f.y; sf[q*4+2] = f.z; sf[q*4+3] = f.w;
            }
        }
        while (mask) {
            int gg = __ffsll(mask) - 1;   // increasing = front-to-back
            mask &= mask - 1;
            float u  = rlf(gu, gg),  v  = rlf(gv, gg);
            float ia = rlf(gia, gg), ib = rlf(gib, gg), ic = rlf(gic, gg);
            float dx = fxp - u, dy = fyp - v;
            float d2 = ia*dx*dx + ic*dy*dy + 2.0f*ib*(dx*dy);
            float gvl = __expf(-0.5f * d2);
            float alpha = fminf(rlf(gop, gg) * gvl, 0.99f);
            float w = T * alpha;
            T -= w;
            accD += w * rlf(gdz, gg);
            accA += w;
#pragma unroll
            for (int ch = 0; ch < MAXC; ++ch) accS[ch] += w * rlf(sf[ch], gg);
        }
    }

    // ---- two-pass segment combine: out_c = sum_w Tprefix(w) * acc_{w,c} ----
    int px = lane;
    int pxx = txi * 8 + (px & 7);
    int pyy = tyi * 8 + (px >> 3);
    bool inb = (pxx < W) && (pyy < H);
    size_t HW  = (size_t)H * W;
    size_t pix = (size_t)pyy * W + pxx;
    size_t BMHW = (size_t)BM * HW;

    // pass 1 rows: 0=T, 1=D, 2=A, 3..8=S0..S5
    float* my = comb + (wave * ROWS1) * 64 + lane;
    my[0 * 64] = T;
    my[1 * 64] = accD;
    my[2 * 64] = accA;
#pragma unroll
    for (int k = 0; k < 6; ++k) my[(3 + k) * 64] = accS[k];
    __syncthreads();

    float pre[NSEG];
    pre[0] = 1.f;
#pragma unroll
    for (int w = 1; w < NSEG; ++w)
        pre[w] = pre[w-1] * comb[((w-1) * ROWS1) * 64 + px];

    {   // pass 1 outputs: wave w handles [depth, sem0..5, alpha][w]
        int row, outc;
        if (wave == 0)      { row = 1;        outc = 0; }       // depth
        else if (wave <= 6) { row = 2 + wave; outc = wave; }    // sem wave-1
        else                { row = 2;        outc = C + 1; }   // alpha
        float val = 0.f;
#pragma unroll
        for (int w = 0; w < NSEG; ++w)
            val += pre[w] * comb[(w * ROWS1 + row) * 64 + px];
        if (inb) {
            float* dst;
            if (outc == 0)      dst = out + (size_t)bm * HW + pix;
            else if (outc <= C) dst = out + BMHW + (size_t)bm * C * HW + (size_t)(outc-1) * HW + pix;
            else                dst = out + BMHW + BMHW * C + (size_t)bm * HW + pix;
            *dst = val;
        }
    }
    __syncthreads();   // pass-1 reads done before overwrite

    // pass 2 rows: 0..9 = S6..S15
    float* my2 = comb + (wave * ROWS2) * 64 + lane;
#pragma unroll
    for (int k = 0; k < 10; ++k) my2[k * 64] = accS[6 + k];
    __syncthreads();

    for (int k = wave; k < 10; k += NSEG) {   // sem6..15
        float val = 0.f;
#pragma unroll
        for (int w = 0; w < NSEG; ++w)
            val += pre[w] * comb[(w * ROWS2 + k) * 64 + px];
        if (inb) {
            int outc = 7 + k;   // sem index 6+k
            float* dst = out + BMHW + (size_t)bm * C * HW + (size_t)(outc-1) * HW + pix;
            *dst = val;
        }
    }
    __syncthreads();   // protect comb reuse across tile-loop iterations
}

// ============================ kernels ============================

__global__ __launch_bounds__(256) void preprocess_kernel(
    const float* __restrict__ means, const float* __restrict__ scales,
    const float* __restrict__ rots,  const float* __restrict__ intr,
    const float* __restrict__ cam2ego,
    int* __restrict__ ikey, float* __restrict__ uu, float* __restrict__ vv,
    float* __restrict__ cia, float* __restrict__ cib, float* __restrict__ cic,
    float* __restrict__ pr2, int B, int M, int N, int W, int H)
{
    __shared__ float Esh[MAXBM * 12];
    int BM = B * M;
    if (threadIdx.x < (unsigned)BM)
        inv4x4_rows3(cam2ego + (size_t)threadIdx.x * 16, Esh + threadIdx.x * 12);
    __syncthreads();
    int gid = blockIdx.x * 256 + threadIdx.x;
    if (gid < BM * N)
        proj_one(gid, M, N, W, H, Esh, means, scales, rots, intr,
                 ikey, uu, vv, cia, cib, cic, pr2);
}

__global__ __launch_bounds__(64) void rankpack_kernel(
    const int* __restrict__ ikey,
    const float* __restrict__ uu, const float* __restrict__ vv,
    const float* __restrict__ cia, const float* __restrict__ cib,
    const float* __restrict__ cic, const float* __restrict__ pr2,
    const float* __restrict__ opac, const float* __restrict__ sem,
    float* __restrict__ pu, float* __restrict__ pv,
    float* __restrict__ pia, float* __restrict__ pib, float* __restrict__ pic,
    float* __restrict__ pop, float* __restrict__ pdz, float* __restrict__ prr,
    float* __restrict__ psem, int* __restrict__ pcount,
    int B, int M, int N, int C)
{
    rank_chunk(blockIdx.x, threadIdx.x & 63, M, N, C, ikey, uu, vv,
               cia, cib, cic, pr2, opac, sem,
               pu, pv, pia, pib, pic, pop, pdz, prr, psem, pcount);
}

__global__ __launch_bounds__(RTPB) void raster_kernel(
    const float* __restrict__ pu, const float* __restrict__ pv,
    const float* __restrict__ pia, const float* __restrict__ pib,
    const float* __restrict__ pic, const float* __restrict__ pop,
    const float* __restrict__ pdz, const float* __restrict__ prr,
    const float* __restrict__ psem, const int* __restrict__ pcount,
    float* __restrict__ out,
    int BM, int N, int C, int H, int W, int ntx, int nty)
{
    __shared__ float comb[NSEG * ROWS2 * 64];
    raster_tile(blockIdx.x, threadIdx.x >> 6, threadIdx.x & 63, comb,
                BM, N, C, H, W, ntx, nty,
                pu, pv, pia, pib, pic, pop, pdz, prr, psem, pcount, out);
}

__global__ __launch_bounds__(RTPB, 4) void fused_kernel(
    const float* __restrict__ means, const float* __restrict__ scales,
    const float* __restrict__ rots,  const float* __restrict__ opac,
    const float* __restrict__ sem,   const float* __restrict__ intr,
    const float* __restrict__ cam2ego,
    int* __restrict__ ikey,
    float* __restrict__ uu, float* __restrict__ vv,
    float* __restrict__ cia, float* __restrict__ cib, float* __restrict__ cic,
    float* __restrict__ pr2,
    float* __restrict__ pu, float* __restrict__ pv,
    float* __restrict__ pia, float* __restrict__ pib, float* __restrict__ pic,
    float* __restrict__ pop, float* __restrict__ pdz, float* __restrict__ prr,
    float* __restrict__ psem, int* __restrict__ pcount,
    float* __restrict__ out,
    int B, int M, int N, int C, int H, int W, int ntx, int nty)
{
    cg::grid_group gridg = cg::this_grid();
    __shared__ float Esh[MAXBM * 12];
    __shared__ float comb[NSEG * ROWS2 * 64];
    int BM   = B * M;
    int tid  = threadIdx.x;
    int wave = tid >> 6;
    int lane = tid & 63;

    // phase A
    if (tid < BM)
        inv4x4_rows3(cam2ego + (size_t)tid * 16, Esh + tid * 12);
    __syncthreads();
    int total = BM * N;
    for (int gid = blockIdx.x * RTPB + tid; gid < total; gid += gridDim.x * RTPB)
        proj_one(gid, M, N, W, H, Esh, means, scales, rots, intr,
                 ikey, uu, vv, cia, cib, cic, pr2);
    gridg.sync();

    // phase B: one wave (wave 0) per 64-i chunk
    int nch64 = (N + 63) >> 6;
    for (int chunk = blockIdx.x; chunk < BM * nch64; chunk += gridDim.x) {
        if (wave == 0)
            rank_chunk(chunk, lane, M, N, C, ikey, uu, vv,
                       cia, cib, cic, pr2, opac, sem,
                       pu, pv, pia, pib, pic, pop, pdz, prr, psem, pcount);
    }
    gridg.sync();

    // phase C
    int ntiles = ntx * nty * BM;
    for (int tile = blockIdx.x; tile < ntiles; tile += gridDim.x)
        raster_tile(tile, wave, lane, comb, BM, N, C, H, W, ntx, nty,
                    pu, pv, pia, pib, pic, pop, pdz, prr, psem, pcount, out);
}

extern "C" void kernel_launch(void* const* d_in, const int* in_sizes, int n_in,
                              void* d_out, int out_size, void* d_ws, size_t ws_size,
                              hipStream_t stream) {
    const float* means  = (const float*)d_in[0];
    const float* scales = (const float*)d_in[1];
    const float* rots   = (const float*)d_in[2];
    const float* opac   = (const float*)d_in[3];
    const float* sem    = (const float*)d_in[4];
    const float* intr   = (const float*)d_in[5];
    const float* c2e    = (const float*)d_in[6];
    float* out = (float*)d_out;

    int B  = 1;
    int BM = in_sizes[6] / 16;         // cam2ego is (B,M,4,4)
    int M  = BM / B;
    int N  = in_sizes[0] / (3 * B);    // means (B,N,3)
    int C  = in_sizes[4] / (B * N);    // semantic_features (B,N,C)
    long HWl = (long)out_size / ((long)BM * (C + 2));
    int H = (int)(sqrt((double)HWl) + 0.5);
    int W = (int)(HWl / H);
    int ntx = (W + 7) / 8, nty = (H + 7) / 8;
    int ntiles = ntx * nty * BM;
    int nch64  = (N + 63) >> 6;

    float* ws = (float*)d_ws;
    size_t off = 0;
    size_t BMN  = (size_t)BM * N;
    int*   ikey = (int*)(ws + off); off += BMN;
    float* uu   = ws + off; off += BMN;
    float* vv   = ws + off; off += BMN;
    float* cia  = ws + off; off += BMN;
    float* cib  = ws + off; off += BMN;
    float* cic  = ws + off; off += BMN;
    float* pr2  = ws + off; off += BMN;
    float* pu   = ws + off; off += BMN;
    float* pv   = ws + off; off += BMN;
    float* pia  = ws + off; off += BMN;
    float* pib  = ws + off; off += BMN;
    float* pic  = ws + off; off += BMN;
    float* pop  = ws + off; off += BMN;
    float* pdz  = ws + off; off += BMN;
    float* prr  = ws + off; off += BMN;
    float* psem = ws + off; off += BMN * C;
    int* pcount = (int*)(ws + off); off += BM;

    // 512 blocks x 512 threads: 2 blocks/CU co-resident (LDS 20.9 KB/block,
    // VGPR capped at 128 by __launch_bounds__(512,4) -> 16 waves/CU).
    int nblk = ntiles < 512 ? ntiles : 512;
    void* args[] = {
        (void*)&means, (void*)&scales, (void*)&rots, (void*)&opac,
        (void*)&sem, (void*)&intr, (void*)&c2e,
        (void*)&ikey, (void*)&uu, (void*)&vv, (void*)&cia, (void*)&cib,
        (void*)&cic, (void*)&pr2, (void*)&pu, (void*)&pv, (void*)&pia,
        (void*)&pib, (void*)&pic, (void*)&pop, (void*)&pdz, (void*)&prr,
        (void*)&psem, (void*)&pcount, (void*)&out,
        (void*)&B, (void*)&M, (void*)&N, (void*)&C, (void*)&H, (void*)&W,
        (void*)&ntx, (void*)&nty
    };
    hipError_t err = hipLaunchCooperativeKernel((void*)fused_kernel, dim3(nblk),
                                                dim3(RTPB), args, 0, stream);
    if (err != hipSuccess) {
        (void)hipGetLastError();   // clear sticky error, use 3-kernel path
        int tot = BM * N;
        preprocess_kernel<<<(tot + 255) / 256, 256, 0, stream>>>(
            means, scales, rots, intr, c2e,
            ikey, uu, vv, cia, cib, cic, pr2, B, M, N, W, H);
        rankpack_kernel<<<BM * nch64, 64, 0, stream>>>(
            ikey, uu, vv, cia, cib, cic, pr2, opac, sem,
            pu, pv, pia, pib, pic, pop, pdz, prr, psem, pcount, B, M, N, C);
        raster_kernel<<<ntiles, RTPB, 0, stream>>>(
            pu, pv, pia, pib, pic, pop, pdz, prr, psem, pcount, out,
            BM, N, C, H, W, ntx, nty);
    }
}

// Round 8
// 131.713 us; speedup vs baseline: 1.9484x; 1.9484x over previous
//
#include <hip/hip_runtime.h>
#include <cmath>

// SemanticDepthRasterizer — 3-kernel pipeline (fusion abandoned: fixed ~85us
// harness overhead doesn't scale with launch count, and whole-kernel regalloc
// of the fused variant spilled the composite arrays — R7 post-mortem).
// K1 preprocess: per-gaussian projection/conic (per-block inv(cam2ego), double).
// K2 rankpack:   O(N^2) rank-by-counting == stable argsort-by-z + visible pack,
//                one wave per 64-i chunk, readlane broadcast, key prefetch.
// K3 raster:     depth-segmented tiled compositing, NSEG=16 segments x 16 waves
//                (1024-thread blocks -> 2x the waves of R5's NSEG=8, half the
//                serial depth), readlane broadcast, tile-rect cull, deferred
//                semantic loads, two-pass prefix-transmittance combine (40KB LDS).

#define MAXC   16     // semantic channels in this problem instance (C==16)
#define MAXBM  8      // max views supported by per-block E cache
#define NSEG   16     // depth segments == waves per raster block
#define RTPB   (NSEG * 64)
#define ROWS1  9      // combine pass 1 rows: T,D,A,S0..S5
#define ROWS2  10     // combine pass 2 rows: S6..S15
#define INVIS_KEY 0x7FFFFFFF

__device__ __forceinline__ float rlf(float x, int l) {
    return __int_as_float(__builtin_amdgcn_readlane(__float_as_int(x), l));
}

// ---- 4x4 inverse (double, adjugate), top-3-rows result ----
__device__ void inv4x4_rows3(const float* __restrict__ src, float* __restrict__ Eout) {
    double m[16];
#pragma unroll
    for (int j = 0; j < 16; ++j) m[j] = (double)src[j];
    double inv[16];
    inv[0]  =  m[5]*m[10]*m[15] - m[5]*m[11]*m[14] - m[9]*m[6]*m[15] + m[9]*m[7]*m[14] + m[13]*m[6]*m[11] - m[13]*m[7]*m[10];
    inv[4]  = -m[4]*m[10]*m[15] + m[4]*m[11]*m[14] + m[8]*m[6]*m[15] - m[8]*m[7]*m[14] - m[12]*m[6]*m[11] + m[12]*m[7]*m[10];
    inv[8]  =  m[4]*m[9]*m[15]  - m[4]*m[11]*m[13] - m[8]*m[5]*m[15] + m[8]*m[7]*m[13] + m[12]*m[5]*m[11] - m[12]*m[7]*m[9];
    inv[12] = -m[4]*m[9]*m[14]  + m[4]*m[10]*m[13] + m[8]*m[5]*m[14] - m[8]*m[6]*m[13] - m[12]*m[5]*m[10] + m[12]*m[6]*m[9];
    inv[1]  = -m[1]*m[10]*m[15] + m[1]*m[11]*m[14] + m[9]*m[2]*m[15] - m[9]*m[3]*m[14] - m[13]*m[2]*m[11] + m[13]*m[3]*m[10];
    inv[5]  =  m[0]*m[10]*m[15] - m[0]*m[11]*m[14] - m[8]*m[2]*m[15] + m[8]*m[3]*m[14] + m[12]*m[2]*m[11] - m[12]*m[3]*m[10];
    inv[9]  = -m[0]*m[9]*m[15]  + m[0]*m[11]*m[13] + m[8]*m[1]*m[15] - m[8]*m[3]*m[13] - m[12]*m[1]*m[11] + m[12]*m[3]*m[9];
    inv[13] =  m[0]*m[9]*m[14]  - m[0]*m[10]*m[13] - m[8]*m[1]*m[14] + m[8]*m[2]*m[13] + m[12]*m[1]*m[10] - m[12]*m[2]*m[9];
    inv[2]  =  m[1]*m[6]*m[15]  - m[1]*m[7]*m[14]  - m[5]*m[2]*m[15] + m[5]*m[3]*m[14] + m[13]*m[2]*m[7]  - m[13]*m[3]*m[6];
    inv[6]  = -m[0]*m[6]*m[15]  + m[0]*m[7]*m[14]  + m[4]*m[2]*m[15] - m[4]*m[3]*m[14] - m[12]*m[2]*m[7]  + m[12]*m[3]*m[6];
    inv[10] =  m[0]*m[5]*m[15]  - m[0]*m[7]*m[13]  - m[4]*m[1]*m[15] + m[4]*m[3]*m[13] + m[12]*m[1]*m[7]  - m[12]*m[3]*m[5];
    inv[14] = -m[0]*m[5]*m[14]  + m[0]*m[6]*m[13]  + m[4]*m[1]*m[14] - m[4]*m[2]*m[13] - m[12]*m[1]*m[6]  + m[12]*m[2]*m[5];
    inv[3]  = -m[1]*m[6]*m[11]  + m[1]*m[7]*m[10]  + m[5]*m[2]*m[11] - m[5]*m[3]*m[10] - m[9]*m[2]*m[7]   + m[9]*m[3]*m[6];
    inv[7]  =  m[0]*m[6]*m[11]  - m[0]*m[7]*m[10]  - m[4]*m[2]*m[11] + m[4]*m[3]*m[10] + m[8]*m[2]*m[7]   - m[8]*m[3]*m[6];
    inv[11] = -m[0]*m[5]*m[11]  + m[0]*m[7]*m[9]   + m[4]*m[1]*m[11] - m[4]*m[3]*m[9]  - m[8]*m[1]*m[7]   + m[8]*m[3]*m[5];
    inv[15] =  m[0]*m[5]*m[10]  - m[0]*m[6]*m[9]   - m[4]*m[1]*m[10] + m[4]*m[2]*m[9]  + m[8]*m[1]*m[6]   - m[8]*m[2]*m[5];
    double det = m[0]*inv[0] + m[1]*inv[4] + m[2]*inv[8] + m[3]*inv[12];
    double rdet = 1.0 / det;
#pragma unroll
    for (int r = 0; r < 3; ++r)
#pragma unroll
        for (int c = 0; c < 4; ++c)
            Eout[r * 4 + c] = (float)(inv[r * 4 + c] * rdet);
}

// ---------------- K1: per-gaussian projection + conic ----------------
__global__ __launch_bounds__(256) void preprocess_kernel(
    const float* __restrict__ means, const float* __restrict__ scales,
    const float* __restrict__ rots,  const float* __restrict__ intr,
    const float* __restrict__ cam2ego,
    int* __restrict__ ikey, float* __restrict__ uu, float* __restrict__ vv,
    float* __restrict__ cia, float* __restrict__ cib, float* __restrict__ cic,
    float* __restrict__ pr2, int B, int M, int N, int W, int H)
{
    __shared__ float Esh[MAXBM * 12];
    int BM = B * M;
    if (threadIdx.x < (unsigned)BM)
        inv4x4_rows3(cam2ego + (size_t)threadIdx.x * 16, Esh + threadIdx.x * 12);
    __syncthreads();

    int gid = blockIdx.x * 256 + threadIdx.x;
    if (gid >= BM * N) return;
    int bm = gid / N;
    int n  = gid - bm * N;
    int b  = bm / M;
    const float* Ep = Esh + bm * 12;
    const float* mp = means + ((size_t)b * N + n) * 3;
    float mx = mp[0], my = mp[1], mz = mp[2];
    float x_c = Ep[0]*mx + Ep[1]*my + Ep[2]*mz  + Ep[3];
    float y_c = Ep[4]*mx + Ep[5]*my + Ep[6]*mz  + Ep[7];
    float z   = Ep[8]*mx + Ep[9]*my + Ep[10]*mz + Ep[11];
    const float* K = intr + (size_t)bm * 16;
    float fx = K[0], fy = K[5], cx = K[2], cy = K[6];
    float zs = fmaxf(z, 1e-4f);
    float u = x_c / zs * fx + cx;
    float v = y_c / zs * fy + cy;
    const float* qp = rots + ((size_t)b * N + n) * 4;
    float qw = qp[0], qx = qp[1], qy = qp[2], qz = qp[3];
    float qn = sqrtf(qw*qw + qx*qx + qy*qy + qz*qz);
    qw /= qn; qx /= qn; qy /= qn; qz /= qn;
    float R00 = 1.f - 2.f*(qy*qy + qz*qz), R01 = 2.f*(qx*qy - qz*qw), R02 = 2.f*(qx*qz + qy*qw);
    float R10 = 2.f*(qx*qy + qz*qw), R11 = 1.f - 2.f*(qx*qx + qz*qz), R12 = 2.f*(qy*qz - qx*qw);
    float R20 = 2.f*(qx*qz - qy*qw), R21 = 2.f*(qy*qz + qx*qw), R22 = 1.f - 2.f*(qx*qx + qy*qy);
    const float* sp = scales + ((size_t)b * N + n) * 3;
    float s0 = sp[0]*sp[0], s1 = sp[1]*sp[1], s2 = sp[2]*sp[2];
    float S00 = R00*R00*s0 + R01*R01*s1 + R02*R02*s2;
    float S01 = R00*R10*s0 + R01*R11*s1 + R02*R12*s2;
    float S02 = R00*R20*s0 + R01*R21*s1 + R02*R22*s2;
    float S11 = R10*R10*s0 + R11*R11*s1 + R12*R12*s2;
    float S12 = R10*R20*s0 + R11*R21*s1 + R12*R22*s2;
    float S22 = R20*R20*s0 + R21*R21*s1 + R22*R22*s2;
    float W00 = Ep[0], W01 = Ep[1], W02 = Ep[2];
    float W10 = Ep[4], W11 = Ep[5], W12 = Ep[6];
    float W20 = Ep[8], W21 = Ep[9], W22 = Ep[10];
    float A00 = W00*S00 + W01*S01 + W02*S02;
    float A01 = W00*S01 + W01*S11 + W02*S12;
    float A02 = W00*S02 + W01*S12 + W02*S22;
    float A10 = W10*S00 + W11*S01 + W12*S02;
    float A11 = W10*S01 + W11*S11 + W12*S12;
    float A12 = W10*S02 + W11*S12 + W12*S22;
    float A20 = W20*S00 + W21*S01 + W22*S02;
    float A21 = W20*S01 + W21*S11 + W22*S12;
    float A22 = W20*S02 + W21*S12 + W22*S22;
    float Sc00 = A00*W00 + A01*W01 + A02*W02;
    float Sc01 = A00*W10 + A01*W11 + A02*W12;
    float Sc02 = A00*W20 + A01*W21 + A02*W22;
    float Sc11 = A10*W10 + A11*W11 + A12*W12;
    float Sc12 = A10*W20 + A11*W21 + A12*W22;
    float Sc22 = A20*W20 + A21*W21 + A22*W22;
    float j00 = fx / zs,  j02 = -fx * x_c / (zs * zs);
    float j11 = fy / zs,  j12 = -fy * y_c / (zs * zs);
    float c00 = j00*j00*Sc00 + 2.f*j00*j02*Sc02 + j02*j02*Sc22;
    float c01 = j00*(Sc01*j11 + Sc02*j12) + j02*(Sc12*j11 + Sc22*j12);
    float c11 = j11*j11*Sc11 + 2.f*j11*j12*Sc12 + j12*j12*Sc22;
    float a  = fmaxf(c00, 0.3f);
    float cc = fmaxf(c11, 0.3f);
    float bb = c01;
    float det = a * cc - bb * bb;
    bool valid = (z > 0.01f) && (det > 1e-8f);
    float det_s = (det > 1e-8f) ? det : 1.0f;
    float ia = cc / det_s, ib = -bb / det_s, ic = a / det_s;
    uu[gid] = u;  vv[gid] = v;
    cia[gid] = ia;  cib[gid] = ib;  cic[gid] = ic;
    // conservative cull radius: lambda_min * dist^2 > 34 -> alpha < ~4e-8
    float dmean = 0.5f * (ia + ic);
    float rad   = sqrtf(fmaxf(0.25f*(ia - ic)*(ia - ic) + ib*ib, 0.f));
    float lmin  = fmaxf(dmean - rad, 1e-12f);
    pr2[gid] = 34.0f / lmin;
    bool visible = valid && (z > 0.1f) &&
                   (u >= 0.f) && (u < (float)W) && (v >= 0.f) && (v < (float)H);
    ikey[gid] = visible ? __float_as_int(z) : INVIS_KEY;
}

// -- K2: rank one 64-i chunk per block (stable argsort by z) + pack --
__global__ __launch_bounds__(64) void rankpack_kernel(
    const int* __restrict__ ikey,
    const float* __restrict__ uu, const float* __restrict__ vv,
    const float* __restrict__ cia, const float* __restrict__ cib,
    const float* __restrict__ cic, const float* __restrict__ pr2,
    const float* __restrict__ opac, const float* __restrict__ sem,
    float* __restrict__ pu, float* __restrict__ pv,
    float* __restrict__ pia, float* __restrict__ pib, float* __restrict__ pic,
    float* __restrict__ pop, float* __restrict__ pdz, float* __restrict__ prr,
    float* __restrict__ psem, int* __restrict__ pcount,
    int B, int M, int N, int C)
{
    int lane  = threadIdx.x & 63;
    int nch64 = (N + 63) >> 6;
    int chunk = blockIdx.x;
    int bm = chunk / nch64;
    int cl = chunk - bm * nch64;          // i-chunk index within view
    int i  = (cl << 6) + lane;
    const int* kb = ikey + (size_t)bm * N;
    int ki  = (i < N) ? kb[i] : INVIS_KEY;
    int kip = ki + 1;                     // tie-break: j<i counts kj<=ki
    int rank = 0, tot = 0;
    int kj = (lane < N) ? kb[lane] : INVIS_KEY;   // prefetched chunk 0
    for (int jc = 0; jc < nch64; ++jc) {
        int kcur = kj;
        if (jc + 1 < nch64) {
            int jn = ((jc + 1) << 6) + lane;
            kj = (jn < N) ? kb[jn] : INVIS_KEY;
        }
        tot += (int)__popcll(__ballot(kcur != INVIS_KEY));
        if (jc < cl) {
#pragma unroll
            for (int gg = 0; gg < 64; ++gg)
                rank += (__builtin_amdgcn_readlane(kcur, gg) < kip);
        } else if (jc > cl) {
#pragma unroll
            for (int gg = 0; gg < 64; ++gg)
                rank += (__builtin_amdgcn_readlane(kcur, gg) < ki);
        } else {            // straddle chunk: j < i  <=>  gg < lane
#pragma unroll
            for (int gg = 0; gg < 64; ++gg) {
                int kk = (gg < lane) ? kip : ki;
                rank += (__builtin_amdgcn_readlane(kcur, gg) < kk);
            }
        }
    }
    if (cl == 0 && lane == 0) pcount[bm] = tot;
    if (i < N && ki != INVIS_KEY) {
        int b = bm / M;
        size_t src = (size_t)bm * N + i;
        size_t dst = (size_t)bm * N + rank;
        pu[dst]  = uu[src];   pv[dst]  = vv[src];
        pia[dst] = cia[src];  pib[dst] = cib[src];  pic[dst] = cic[src];
        pop[dst] = opac[(size_t)b * N + i];
        float z  = __int_as_float(ki);
        pdz[dst] = fminf(fmaxf(z, 0.1f), 100.0f);
        prr[dst] = pr2[src];
        const float* spc = sem + ((size_t)b * N + i) * C;
        float* dpc = psem + dst * C;
        int c4 = C & ~3;
        for (int q = 0; q < c4; q += 4)
            *(float4*)(dpc + q) = *(const float4*)(spc + q);
        for (int q = c4; q < C; ++q) dpc[q] = spc[q];
    }
}

// ---- K3: one 8x8 tile per block, 16 depth segments x 16 waves ----
__global__ __launch_bounds__(RTPB) void raster_kernel(
    const float* __restrict__ pu, const float* __restrict__ pv,
    const float* __restrict__ pia, const float* __restrict__ pib,
    const float* __restrict__ pic, const float* __restrict__ pop,
    const float* __restrict__ pdz, const float* __restrict__ prr,
    const float* __restrict__ psem, const int* __restrict__ pcount,
    float* __restrict__ out,
    int BM, int N, int C, int H, int W, int ntx, int nty)
{
    __shared__ float comb[NSEG * ROWS2 * 64];   // 40 KB; pass1 uses ROWS1 rows
    int wave = threadIdx.x >> 6;
    int lane = threadIdx.x & 63;
    int tile = blockIdx.x;
    int tpv = ntx * nty;
    int bm  = tile / tpv;
    int rem = tile - bm * tpv;
    int tyi = rem / ntx;
    int txi = rem - tyi * ntx;
    int lx = lane & 7, ly = lane >> 3;
    float fxp = (float)(txi * 8 + lx), fyp = (float)(tyi * 8 + ly);
    float x0 = (float)(txi * 8),     y0 = (float)(tyi * 8);
    float x1 = (float)(txi * 8 + 7), y1 = (float)(tyi * 8 + 7);

    int cnt = pcount[bm];
    int seg = (cnt + NSEG - 1) / NSEG;
    int gs = wave * seg;
    int ge = min(gs + seg, cnt);

    float T = 1.0f, accA = 0.f, accD = 0.f;
    float accS[MAXC];
#pragma unroll
    for (int q = 0; q < MAXC; ++q) accS[q] = 0.f;

    for (int base = gs; base < ge; base += 64) {
        if (!__any(T >= 1e-6f)) break;
        int g = base + lane;
        bool inr = g < ge;
        size_t src = (size_t)bm * N + g;
        float gu = 1e30f, gv = 1e30f, gia = 0.f, gib = 0.f, gic = 0.f,
              gop = 0.f, gdz = 0.f, gr2 = -1.f;
        if (inr) {
            gu  = pu[src];  gv  = pv[src];
            gia = pia[src]; gib = pib[src]; gic = pic[src];
            gop = pop[src]; gdz = pdz[src]; gr2 = prr[src];
        }
        // tile cull: dist^2 from tile rect to center vs r2
        float cxm = fminf(fmaxf(gu, x0), x1);
        float cym = fminf(fmaxf(gv, y0), y1);
        float ddx = gu - cxm, ddy = gv - cym;
        float dist2 = ddx*ddx + ddy*ddy;
        unsigned long long mask = __ballot(inr && (dist2 <= gr2));
        // deferred semantic load: only survivors fetch their channels
        float sf[MAXC];
        if ((mask >> lane) & 1ull) {
            const float4* spc = (const float4*)(psem + src * MAXC);
#pragma unroll
            for (int q = 0; q < MAXC / 4; ++q) {
                float4 f = spc[q];
                sf[q*4+0] = f.x; sf[q*4+1] = f.y; sf[q*4+2] = f.z; sf[q*4+3] = f.w;
            }
        }
        while (mask) {
            int gg = __ffsll(mask) - 1;   // increasing = front-to-back
            mask &= mask - 1;
            float u  = rlf(gu, gg),  v  = rlf(gv, gg);
            float ia = rlf(gia, gg), ib = rlf(gib, gg), ic = rlf(gic, gg);
            float dx = fxp - u, dy = fyp - v;
            float d2 = ia*dx*dx + ic*dy*dy + 2.0f*ib*(dx*dy);
            float gvl = __expf(-0.5f * d2);
            float alpha = fminf(rlf(gop, gg) * gvl, 0.99f);
            float w = T * alpha;
            T -= w;
            accD += w * rlf(gdz, gg);
            accA += w;
#pragma unroll
            for (int ch = 0; ch < MAXC; ++ch) accS[ch] += w * rlf(sf[ch], gg);
        }
    }

    // ---- two-pass segment combine: out_c = sum_w Tprefix(w) * acc_{w,c} ----
    int px = lane;
    int pxx = txi * 8 + (px & 7);
    int pyy = tyi * 8 + (px >> 3);
    bool inb = (pxx < W) && (pyy < H);
    size_t HW  = (size_t)H * W;
    size_t pix = (size_t)pyy * W + pxx;
    size_t BMHW = (size_t)BM * HW;

    // pass 1 rows: 0=T, 1=D, 2=A, 3..8=S0..S5
    float* my = comb + (wave * ROWS1) * 64 + lane;
    my[0 * 64] = T;
    my[1 * 64] = accD;
    my[2 * 64] = accA;
#pragma unroll
    for (int k = 0; k < 6; ++k) my[(3 + k) * 64] = accS[k];
    __syncthreads();

    float pre[NSEG];
    pre[0] = 1.f;
#pragma unroll
    for (int w = 1; w < NSEG; ++w)
        pre[w] = pre[w-1] * comb[((w-1) * ROWS1) * 64 + px];

    if (wave < 8) {   // pass 1 outputs: depth, sem0..5, alpha
        int row, outc;
        if (wave == 0)      { row = 1;        outc = 0; }       // depth
        else if (wave <= 6) { row = 2 + wave; outc = wave; }    // sem wave-1
        else                { row = 2;        outc = C + 1; }   // alpha
        float val = 0.f;
#pragma unroll
        for (int w = 0; w < NSEG; ++w)
            val += pre[w] * comb[(w * ROWS1 + row) * 64 + px];
        if (inb) {
            float* dst;
            if (outc == 0)      dst = out + (size_t)bm * HW + pix;
            else if (outc <= C) dst = out + BMHW + (size_t)bm * C * HW + (size_t)(outc-1) * HW + pix;
            else                dst = out + BMHW + BMHW * C + (size_t)bm * HW + pix;
            *dst = val;
        }
    }
    __syncthreads();   // pass-1 reads done before overwrite

    // pass 2 rows: 0..9 = S6..S15
    float* my2 = comb + (wave * ROWS2) * 64 + lane;
#pragma unroll
    for (int k = 0; k < 10; ++k) my2[k * 64] = accS[6 + k];
    __syncthreads();

    if (wave < 10) {   // sem6..15
        int k = wave;
        float val = 0.f;
#pragma unroll
        for (int w = 0; w < NSEG; ++w)
            val += pre[w] * comb[(w * ROWS2 + k) * 64 + px];
        if (inb) {
            int outc = 7 + k;   // sem index 6+k
            float* dst = out + BMHW + (size_t)bm * C * HW + (size_t)(outc-1) * HW + pix;
            *dst = val;
        }
    }
}

extern "C" void kernel_launch(void* const* d_in, const int* in_sizes, int n_in,
                              void* d_out, int out_size, void* d_ws, size_t ws_size,
                              hipStream_t stream) {
    const float* means  = (const float*)d_in[0];
    const float* scales = (const float*)d_in[1];
    const float* rots   = (const float*)d_in[2];
    const float* opac   = (const float*)d_in[3];
    const float* sem    = (const float*)d_in[4];
    const float* intr   = (const float*)d_in[5];
    const float* c2e    = (const float*)d_in[6];
    float* out = (float*)d_out;

    int B  = 1;
    int BM = in_sizes[6] / 16;         // cam2ego is (B,M,4,4)
    int M  = BM / B;
    int N  = in_sizes[0] / (3 * B);    // means (B,N,3)
    int C  = in_sizes[4] / (B * N);    // semantic_features (B,N,C)
    long HWl = (long)out_size / ((long)BM * (C + 2));
    int H = (int)(sqrt((double)HWl) + 0.5);
    int W = (int)(HWl / H);
    int ntx = (W + 7) / 8, nty = (H + 7) / 8;
    int ntiles = ntx * nty * BM;
    int nch64  = (N + 63) >> 6;

    float* ws = (float*)d_ws;
    size_t off = 0;
    size_t BMN  = (size_t)BM * N;
    int*   ikey = (int*)(ws + off); off += BMN;
    float* uu   = ws + off; off += BMN;
    float* vv   = ws + off; off += BMN;
    float* cia  = ws + off; off += BMN;
    float* cib  = ws + off; off += BMN;
    float* cic  = ws + off; off += BMN;
    float* pr2  = ws + off; off += BMN;
    float* pu   = ws + off; off += BMN;
    float* pv   = ws + off; off += BMN;
    float* pia  = ws + off; off += BMN;
    float* pib  = ws + off; off += BMN;
    float* pic  = ws + off; off += BMN;
    float* pop  = ws + off; off += BMN;
    float* pdz  = ws + off; off += BMN;
    float* prr  = ws + off; off += BMN;
    float* psem = ws + off; off += BMN * C;
    int* pcount = (int*)(ws + off); off += BM;

    int tot = BM * N;
    preprocess_kernel<<<(tot + 255) / 256, 256, 0, stream>>>(
        means, scales, rots, intr, c2e,
        ikey, uu, vv, cia, cib, cic, pr2, B, M, N, W, H);

    rankpack_kernel<<<BM * nch64, 64, 0, stream>>>(
        ikey, uu, vv, cia, cib, cic, pr2, opac, sem,
        pu, pv, pia, pib, pic, pop, pdz, prr, psem, pcount, B, M, N, C);

    raster_kernel<<<ntiles, RTPB, 0, stream>>>(
        pu, pv, pia, pib, pic, pop, pdz, prr, psem, pcount, out,
        BM, N, C, H, W, ntx, nty);
}